// Round 10
// baseline (486.247 us; speedup 1.0000x reference)
//
#include <hip/hip_runtime.h>
#include <hip/hip_bf16.h>
#include <math.h>

#define SEQ   2048
#define HID   4096
#define NHEAD 32
#define HD    128
#define QKVN  12288

typedef __bf16 bf16;
typedef __bf16 bf16x8 __attribute__((ext_vector_type(8)));
typedef __bf16 bf16x4 __attribute__((ext_vector_type(4)));
typedef float  f32x4  __attribute__((ext_vector_type(4)));

#define AS1 __attribute__((address_space(1)))
#define AS3 __attribute__((address_space(3)))

__device__ __forceinline__ void gload16(const void* g, void* l) {
    __builtin_amdgcn_global_load_lds((const AS1 void*)g, (AS3 void*)l, 16, 0, 0);
}

__device__ __forceinline__ unsigned short bbits(bf16 b) {
    union { bf16 b; unsigned short u; } x; x.b = b; return x.u;
}

// ========== 256x192 2-phase bf16 GEMM (tail-free grid): C = A @ Bt^T ==========
// 8 waves, BK=64, 112KB LDS dbuf. Grid 8x64 = 512 blocks = EXACTLY 2 dispatch
// rounds on 256 CUs (round-9's 384-block grid wasted 25% in the tail round).
// Wave (wr=wave>>2, wc=wave&3) per phase mh owns rows mh*128+wr*64..+64 x
// cols wc*48..+48 (4x3 frags). B-frags loaded ONCE per tile, reused across both
// mh phases => 22 ds_read_b128 : 48 MFMA per tile, 24 MFMA per barrier-pair.
// vmcnt invariant (phase p's vmcnt protects phase p+1's reads), hand-traced:
//   prologue: 3B(0),4A(0), vmcnt(2)  [leaves A2,A3(0)]
//   mh0: stage 3B(Y), vmcnt(3)       [drains A2,A3(X) for mh1's reads]
//   mh1: stage 4A(Y), vmcnt(2)       [drains B(Y),A0,A1(Y) for next mh0]
//   peel: vmcnt(0) / nop.
// amdgpu_waves_per_eu(2,2) pins the 256-VGPR budget (round-9 lesson).
__global__ __launch_bounds__(512) __attribute__((amdgpu_waves_per_eu(2, 2)))
void gemm192(const bf16* __restrict__ A, const bf16* __restrict__ Bt,
             bf16* __restrict__ C, int M, int N, int K) {
    __shared__ __attribute__((aligned(16))) char lds[114688];
    // A: [buf][256 rows][128B] at buf*32768 ; B: [buf][192 rows][128B] at 65536+buf*24576
    const int tid  = threadIdx.x;
    const int l    = tid & 63;
    const int wave = tid >> 6;      // 0..7
    const int wr   = wave >> 2;     // 0..1
    const int wc   = wave & 3;      // 0..3
    const int lh   = l >> 4;        // 0..3
    const int ll   = l & 15;
    const int by   = blockIdx.x & 7, bx = blockIdx.x >> 3;   // by=XCD: A-panel L2-resident
    const int brow = by * 256, bcol = bx * 192;

    f32x4 acc[2][4][3];             // [mh][f(row frag)][g(col frag)] = 96 f32
    #pragma unroll
    for (int m = 0; m < 2; ++m)
        #pragma unroll
        for (int f = 0; f < 4; ++f)
            #pragma unroll
            for (int g = 0; g < 3; ++g) acc[m][f][g] = (f32x4){0.f, 0.f, 0.f, 0.f};

    // staging: thread stages LDS bytes trow*128 + tslot*16 of a 64-row unit;
    // global source k-slot = tslot ^ (trow&7) (pre-swizzled source).
    const int trow = tid >> 3, tslot = tid & 7;
    const int srcs = (tslot ^ (trow & 7)) * 16;
    const size_t rowb = (size_t)K * 2;
    const char* pA[4]; const char* pB[3];
    #pragma unroll
    for (int i = 0; i < 4; ++i)
        pA[i] = (const char*)A + (size_t)(brow + i*64 + trow) * rowb + srcs;
    #pragma unroll
    for (int i = 0; i < 3; ++i)
        pB[i] = (const char*)Bt + (size_t)(bcol + i*64 + trow) * rowb + srcs;

#define SAU(buf, i) do { \
        gload16(pA[i], lds + (buf)*32768 + (i)*8192 + tid*16); pA[i] += 128; \
    } while (0)
#define SBU(buf, i) do { \
        gload16(pB[i], lds + 65536 + (buf)*24576 + (i)*8192 + tid*16); pB[i] += 128; \
    } while (0)

    const int sw0 = ((0 + lh) ^ (ll & 7)) << 4;     // k-slice 0 swizzled slot byte
    const int sw1 = ((4 + lh) ^ (ll & 7)) << 4;     // k-slice 1

    bf16x8 af[4][2], bv[3][2];      // bv persists across both mh phases

#define LOADA(Xb, mh) do { \
        const char* LA_ = lds + (Xb)*32768 + ((mh)*128 + wr*64 + ll)*128; \
        _Pragma("unroll") \
        for (int f_ = 0; f_ < 4; ++f_) { \
            af[f_][0] = *(const bf16x8*)(LA_ + f_*2048 + sw0); \
            af[f_][1] = *(const bf16x8*)(LA_ + f_*2048 + sw1); \
        } \
    } while (0)
#define LOADB(Xb) do { \
        const char* LB_ = lds + 65536 + (Xb)*24576 + (wc*48 + ll)*128; \
        _Pragma("unroll") \
        for (int g_ = 0; g_ < 3; ++g_) { \
            bv[g_][0] = *(const bf16x8*)(LB_ + g_*2048 + sw0); \
            bv[g_][1] = *(const bf16x8*)(LB_ + g_*2048 + sw1); \
        } \
    } while (0)
#define FENCE_MMA(WAITSTR, mh) do { \
        asm volatile(WAITSTR ::: "memory"); \
        __builtin_amdgcn_s_barrier(); \
        asm volatile("s_waitcnt lgkmcnt(0)" ::: "memory"); \
        __builtin_amdgcn_sched_barrier(0); \
        __builtin_amdgcn_s_setprio(1); \
        _Pragma("unroll") \
        for (int f_ = 0; f_ < 4; ++f_) \
            _Pragma("unroll") \
            for (int g_ = 0; g_ < 3; ++g_) { \
                acc[mh][f_][g_] = __builtin_amdgcn_mfma_f32_16x16x32_bf16( \
                    af[f_][0], bv[g_][0], acc[mh][f_][g_], 0, 0, 0); \
                acc[mh][f_][g_] = __builtin_amdgcn_mfma_f32_16x16x32_bf16( \
                    af[f_][1], bv[g_][1], acc[mh][f_][g_], 0, 0, 0); \
            } \
        __builtin_amdgcn_s_setprio(0); \
        __builtin_amdgcn_s_barrier(); \
    } while (0)

    // prologue: 3B(0)+4A(0); vmcnt(2) leaves A2,A3(0) in flight.
    SBU(0, 0); SBU(0, 1); SBU(0, 2);
    SAU(0, 0); SAU(0, 1); SAU(0, 2); SAU(0, 3);
    asm volatile("s_waitcnt vmcnt(2)" ::: "memory");
    __builtin_amdgcn_s_barrier();

    const int NT = K >> 6;
    for (int u = 0; u < NT - 1; ++u) {
        const int X = u & 1, Y = X ^ 1;
        // mh0: reads A half-0 + all B; stage next-tile B.
        LOADA(X, 0); LOADB(X);
        SBU(Y, 0); SBU(Y, 1); SBU(Y, 2);
        FENCE_MMA("s_waitcnt vmcnt(3)", 0);
        // mh1: reads A half-1 (bv reused); stage next-tile A.
        LOADA(X, 1);
        SAU(Y, 0); SAU(Y, 1); SAU(Y, 2); SAU(Y, 3);
        FENCE_MMA("s_waitcnt vmcnt(2)", 1);
    }
    {   // peeled last tile
        const int X = (NT - 1) & 1;
        LOADA(X, 0); LOADB(X);
        FENCE_MMA("s_waitcnt vmcnt(0)", 0);
        LOADA(X, 1);
        FENCE_MMA("s_nop 0", 1);
    }
#undef FENCE_MMA
#undef LOADA
#undef LOADB
#undef SAU
#undef SBU

    // ---------- epilogue: per-wave LDS staging (tile buffers dead) ----------
    __syncthreads();
    float* ep = (float*)lds + wave * (16 * 52);   // 16 rows x 52 stride f32 per wave
    #pragma unroll
    for (int mh = 0; mh < 2; ++mh) {
        #pragma unroll
        for (int f = 0; f < 4; ++f) {
            #pragma unroll
            for (int g = 0; g < 3; ++g)
                #pragma unroll
                for (int j = 0; j < 4; ++j)
                    ep[(lh*4 + j) * 52 + g*16 + ll] = acc[mh][f][g][j];
            #pragma unroll
            for (int it = 0; it < 3; ++it) {
                int row = l >> 2;
                int c4  = (l & 3) + it * 4;          // 12 chunks of 4 f32
                const float* src = ep + row * 52 + c4 * 4;
                bf16x4 o = {(bf16)src[0], (bf16)src[1], (bf16)src[2], (bf16)src[3]};
                size_t grow = (size_t)(brow + mh*128 + wr*64 + f*16 + row);
                *(bf16x4*)(C + grow * N + bcol + wc*48 + c4*4) = o;
            }
        }
    }
}

// ========== 256x128 2-phase bf16 GEMM (proven; O-projection) ==========
template<int OB>
__global__ __launch_bounds__(512, 2) void gemm2p(const bf16* __restrict__ A,
                                                 const bf16* __restrict__ Bt,
                                                 void* __restrict__ Cv,
                                                 int M, int N, int K) {
    __shared__ __attribute__((aligned(16))) char lds[98304];
    const int tid  = threadIdx.x;
    const int l    = tid & 63;
    const int wave = tid >> 6;
    const int wr   = wave >> 2;
    const int wc   = wave & 3;
    const int lh   = l >> 4;
    const int ll   = l & 15;

    const int by   = blockIdx.x & 7;
    const int bx   = blockIdx.x >> 3;
    const int brow = by * 256, bcol = bx * 128;

    f32x4 acc[2][4][2];
    #pragma unroll
    for (int m = 0; m < 2; ++m)
        #pragma unroll
        for (int f = 0; f < 4; ++f)
            #pragma unroll
            for (int g = 0; g < 2; ++g) acc[m][f][g] = (f32x4){0.f, 0.f, 0.f, 0.f};

    const int trow = tid >> 3, tslot = tid & 7;
    const int srcs = (tslot ^ (trow & 7)) * 16;
    const size_t rowb = (size_t)K * 2;
    const char* pA[2][2]; const char* pB[2];
    #pragma unroll
    for (int h = 0; h < 2; ++h)
        #pragma unroll
        for (int i = 0; i < 2; ++i)
            pA[h][i] = (const char*)A + (size_t)(brow + h*128 + i*64 + trow) * rowb + srcs;
    #pragma unroll
    for (int i = 0; i < 2; ++i)
        pB[i] = (const char*)Bt + (size_t)(bcol + i*64 + trow) * rowb + srcs;

#define SA(buf, h) do { \
        gload16(pA[h][0], lds + (buf)*32768 + (h)*16384 + tid*16); \
        gload16(pA[h][1], lds + (buf)*32768 + (h)*16384 + 8192 + tid*16); \
        pA[h][0] += 128; pA[h][1] += 128; \
    } while (0)
#define SB(buf) do { \
        gload16(pB[0], lds + 65536 + (buf)*16384 + tid*16); \
        gload16(pB[1], lds + 65536 + (buf)*16384 + 8192 + tid*16); \
        pB[0] += 128; pB[1] += 128; \
    } while (0)

    const int sw0 = ((0 + lh) ^ (ll & 7)) << 4;
    const int sw1 = ((4 + lh) ^ (ll & 7)) << 4;

#define PHASE(Xb, mh, STAGE_STMT, WAITSTR) do { \
        const char* LA_ = lds + (Xb)*32768 + (mh)*16384 + (wr*64 + ll)*128; \
        const char* LB_ = lds + 65536 + (Xb)*16384 + (wc*32 + ll)*128; \
        bf16x8 af_[4][2], bv_[2][2]; \
        _Pragma("unroll") \
        for (int f_ = 0; f_ < 4; ++f_) { \
            af_[f_][0] = *(const bf16x8*)(LA_ + f_*2048 + sw0); \
            af_[f_][1] = *(const bf16x8*)(LA_ + f_*2048 + sw1); \
        } \
        _Pragma("unroll") \
        for (int g_ = 0; g_ < 2; ++g_) { \
            bv_[g_][0] = *(const bf16x8*)(LB_ + g_*2048 + sw0); \
            bv_[g_][1] = *(const bf16x8*)(LB_ + g_*2048 + sw1); \
        } \
        STAGE_STMT; \
        asm volatile(WAITSTR ::: "memory"); \
        __builtin_amdgcn_s_barrier(); \
        asm volatile("s_waitcnt lgkmcnt(0)" ::: "memory"); \
        __builtin_amdgcn_sched_barrier(0); \
        __builtin_amdgcn_s_setprio(1); \
        _Pragma("unroll") \
        for (int f_ = 0; f_ < 4; ++f_) \
            _Pragma("unroll") \
            for (int g_ = 0; g_ < 2; ++g_) { \
                acc[mh][f_][g_] = __builtin_amdgcn_mfma_f32_16x16x32_bf16( \
                    af_[f_][0], bv_[g_][0], acc[mh][f_][g_], 0, 0, 0); \
                acc[mh][f_][g_] = __builtin_amdgcn_mfma_f32_16x16x32_bf16( \
                    af_[f_][1], bv_[g_][1], acc[mh][f_][g_], 0, 0, 0); \
            } \
        __builtin_amdgcn_s_setprio(0); \
        __builtin_amdgcn_s_barrier(); \
    } while (0)

    SA(0, 0); SB(0); SA(0, 1); SA(1, 0);
    asm volatile("s_waitcnt vmcnt(4)" ::: "memory");
    __builtin_amdgcn_s_barrier();

    const int NT = K >> 6;
    for (int u = 0; u < NT - 2; ++u) {
        const int X = u & 1, Y = X ^ 1;
        PHASE(X, 0, SB(Y), "s_waitcnt vmcnt(4)");
        PHASE(X, 1, { SA(Y, 1); SA(X, 0); }, "s_waitcnt vmcnt(4)");
    }
    {
        const int X = (NT - 2) & 1, Y = X ^ 1;
        PHASE(X, 0, SB(Y), "s_waitcnt vmcnt(4)");
        PHASE(X, 1, SA(Y, 1), "s_waitcnt vmcnt(2)");
    }
    {
        const int X = (NT - 1) & 1;
        PHASE(X, 0, ((void)0), "s_waitcnt vmcnt(0)");
        PHASE(X, 1, ((void)0), "s_nop 0");
    }
#undef PHASE
#undef SA
#undef SB

    __syncthreads();
    float* ep = (float*)lds + wave * 2304;
    const int cq = l & 3;
    #pragma unroll
    for (int mh = 0; mh < 2; ++mh) {
        #pragma unroll
        for (int f = 0; f < 4; ++f)
            #pragma unroll
            for (int g = 0; g < 2; ++g)
                #pragma unroll
                for (int j = 0; j < 4; ++j)
                    ep[(f*16 + lh*4 + j) * 36 + g*16 + ll] = acc[mh][f][g][j];
        #pragma unroll
        for (int it = 0; it < 4; ++it) {
            int r2 = it * 16 + (l >> 2);
            const float* src = ep + r2 * 36 + cq * 8;
            size_t grow = (size_t)(brow + mh*128 + wr*64 + r2);
            int gcol = bcol + wc*32 + cq*8;
            if (OB == 0) {
                float* dst = (float*)Cv + grow * N + gcol;
                *(f32x4*)dst       = *(const f32x4*)src;
                *(f32x4*)(dst + 4) = *(const f32x4*)(src + 4);
            } else {
                bf16x8 o;
                #pragma unroll
                for (int jj = 0; jj < 8; ++jj) o[jj] = (bf16)src[jj];
                *(bf16x8*)((bf16*)Cv + grow * N + gcol) = o;
            }
        }
    }
}

// ---------------- f32 -> bf16 flat cast (8/thread) ----------------
__global__ __launch_bounds__(256) void cast_flat(const float* __restrict__ in,
                                                 bf16* __restrict__ out, int n8) {
    int i = blockIdx.x * 256 + threadIdx.x;
    if (i >= n8) return;
    float4 a = ((const float4*)in)[2 * i];
    float4 b = ((const float4*)in)[2 * i + 1];
    bf16x8 o = {(bf16)a.x, (bf16)a.y, (bf16)a.z, (bf16)a.w,
                (bf16)b.x, (bf16)b.y, (bf16)b.z, (bf16)b.w};
    *(bf16x8*)(out + (size_t)i * 8) = o;
}

// ---------------- f32 [R][C] -> bf16 [C][R] transpose-cast ----------------
__global__ __launch_bounds__(256) void cast_transpose(const float* __restrict__ in,
                                                      bf16* __restrict__ out, int R, int C) {
    __shared__ float t[64][65];
    const int r0 = blockIdx.y * 64, c0 = blockIdx.x * 64;
    #pragma unroll
    for (int i = 0; i < 4; ++i) {
        int idx = i * 256 + threadIdx.x;
        int rr = idx >> 4, c4 = (idx & 15) * 4;
        float4 v = *(const float4*)&in[(size_t)(r0 + rr) * C + c0 + c4];
        t[rr][c4] = v.x; t[rr][c4 + 1] = v.y; t[rr][c4 + 2] = v.z; t[rr][c4 + 3] = v.w;
    }
    __syncthreads();
    #pragma unroll
    for (int i = 0; i < 2; ++i) {
        int idx = i * 256 + threadIdx.x;
        int rr = idx >> 3, c8 = (idx & 7) * 8;
        bf16x8 o;
        #pragma unroll
        for (int j = 0; j < 8; ++j) o[j] = (bf16)t[c8 + j][rr];
        *(bf16x8*)&out[(size_t)(c0 + rr) * R + r0 + c8] = o;
    }
}

// ---------------- RoPE trig table ----------------
__global__ __launch_bounds__(256) void rope_table(const int* __restrict__ pos_ids,
                                                  float2* __restrict__ tab) {
    int id = blockIdx.x * 256 + threadIdx.x;   // SEQ*64
    int s = id >> 6, d = id & 63;
    float pos = (float)pos_ids[s];
    float inv = expf(-9.210340371976184f * ((float)d * (1.0f / 64.0f)));
    float sn, cs;
    sincosf(pos * inv, &sn, &cs);
    tab[id] = make_float2(cs, sn);
}

// ---------------- RoPE (NeoX) + repack q,k -> [head][seq][hd] ----------------
__global__ __launch_bounds__(256) void rope_repack(const bf16* __restrict__ qkv,
                                                   const float2* __restrict__ tab,
                                                   bf16* __restrict__ Qb,
                                                   bf16* __restrict__ Kb) {
    int id = blockIdx.x * 256 + threadIdx.x;   // SEQ*NHEAD*16
    const int d4 = (id & 15) * 4;
    const int h  = (id >> 4) & (NHEAD - 1);
    const int s  = id >> 9;

    float2 tr[4];
    #pragma unroll
    for (int i = 0; i < 4; ++i) tr[i] = tab[s * 64 + d4 + i];

    const bf16* row = qkv + (size_t)s * QKVN;
    {
        bf16x4 lo = *(const bf16x4*)(row + h * HD + d4);
        bf16x4 hi = *(const bf16x4*)(row + h * HD + 64 + d4);
        bf16x4 olo, ohi;
        #pragma unroll
        for (int i = 0; i < 4; ++i) {
            float x1 = (float)lo[i], x2 = (float)hi[i];
            olo[i] = (bf16)(x1 * tr[i].x - x2 * tr[i].y);
            ohi[i] = (bf16)(x2 * tr[i].x + x1 * tr[i].y);
        }
        bf16* qo = Qb + ((size_t)h * SEQ + s) * HD;
        *(bf16x4*)(qo + d4) = olo;
        *(bf16x4*)(qo + 64 + d4) = ohi;
    }
    {
        bf16x4 lo = *(const bf16x4*)(row + HID + h * HD + d4);
        bf16x4 hi = *(const bf16x4*)(row + HID + h * HD + 64 + d4);
        bf16x4 olo, ohi;
        #pragma unroll
        for (int i = 0; i < 4; ++i) {
            float x1 = (float)lo[i], x2 = (float)hi[i];
            olo[i] = (bf16)(x1 * tr[i].x - x2 * tr[i].y);
            ohi[i] = (bf16)(x2 * tr[i].x + x1 * tr[i].y);
        }
        bf16* ko = Kb + ((size_t)h * SEQ + s) * HD;
        *(bf16x4*)(ko + d4) = olo;
        *(bf16x4*)(ko + 64 + d4) = ohi;
    }
}

// ---------------- V transpose: qkv v-slice -> Vt [head][hd][seq] ----------------
__global__ __launch_bounds__(256) void v_transpose(const bf16* __restrict__ qkv,
                                                   bf16* __restrict__ Vt) {
    __shared__ bf16 t[64][130];
    const int h = blockIdx.y, s0 = blockIdx.x * 64;
    #pragma unroll
    for (int i = 0; i < 4; ++i) {
        int idx = i * 256 + threadIdx.x;
        int ss = idx >> 4, c8 = (idx & 15) * 8;
        bf16x8 v = *(const bf16x8*)&qkv[(size_t)(s0 + ss) * QKVN + 2 * HID + h * HD + c8];
        #pragma unroll
        for (int j = 0; j < 8; ++j) t[ss][c8 + j] = v[j];
    }
    __syncthreads();
    #pragma unroll
    for (int i = 0; i < 4; ++i) {
        int idx = i * 256 + threadIdx.x;
        int dd = idx >> 3, s8 = (idx & 7) * 8;
        bf16x8 o;
        #pragma unroll
        for (int j = 0; j < 8; ++j) o[j] = t[s8 + j][dd];
        *(bf16x8*)&Vt[((size_t)h * HD + dd) * SEQ + s0 + s8] = o;
    }
}

// ---------------- bf16 MFMA causal flash attention, 2-phase K/V dbuf ----------------
__global__ __launch_bounds__(256) void attn_mfma(const bf16* __restrict__ Qb,
                                                 const bf16* __restrict__ Kb,
                                                 const bf16* __restrict__ Vt,
                                                 bf16* __restrict__ attn) {
    __shared__ __attribute__((aligned(16))) char Ka[2][16384];
    __shared__ __attribute__((aligned(16))) char Va[2][16384];
    __shared__ __attribute__((aligned(16))) char Ps[4 * 2048];
    const int tid  = threadIdx.x, l = tid & 63, wave = tid >> 6;
    const int head = blockIdx.x;
    const int qb   = gridDim.y - 1 - blockIdx.y;
    const int q0   = qb * 64;
    const int qw   = q0 + wave * 16;
    const float scale = 0.08838834764831845f;

    bf16x8 qf[4];
    const bf16* Qg = Qb + ((size_t)head * SEQ + qw + (l & 15)) * HD;
    #pragma unroll
    for (int kc = 0; kc < 4; ++kc) qf[kc] = *(const bf16x8*)(Qg + kc * 32 + (l >> 4) * 8);

    f32x4 o[8];
    #pragma unroll
    for (int i = 0; i < 8; ++i) o[i] = (f32x4){0.f, 0.f, 0.f, 0.f};
    float mrun = -1e30f, lrun = 0.f;
    const int qrow  = qw + (l & 15);
    const int ntile = qb + 1;

    const char* Kg = (const char*)(Kb + (size_t)head * SEQ * HD);
    const char* Vg = (const char*)(Vt + (size_t)head * HD * SEQ);
    char* Pw = Ps + wave * 2048;

#define ASTAGE(b, t0) do { \
        const int kv0_ = (t0) * 64; \
        _Pragma("unroll") \
        for (int i = 0; i < 4; ++i) { \
            int c = i * 256 + tid; \
            int rk_ = c >> 4, slk_ = c & 15; \
            gload16(Kg + (size_t)(kv0_ + rk_) * 256 + ((slk_ * 16) ^ ((rk_ & 15) << 4)), \
                    Ka[b] + (size_t)(i * 256 + (tid & 192)) * 16); \
            int rv_ = c >> 3, slv_ = c & 7; \
            gload16(Vg + (size_t)rv_ * (SEQ * 2) + (size_t)kv0_ * 2 + ((slv_ * 16) ^ ((rv_ & 7) << 4)), \
                    Va[b] + (size_t)(i * 256 + (tid & 192)) * 16); \
        } \
    } while (0)

    ASTAGE(0, 0);
    asm volatile("s_waitcnt vmcnt(0)" ::: "memory");
    __builtin_amdgcn_s_barrier();

    for (int t = 0; t < ntile; ++t) {
        const int cur = t & 1;
        const int kv0 = t * 64;
        if (t + 1 < ntile) ASTAGE(cur ^ 1, t + 1);

        f32x4 st[4];
        __builtin_amdgcn_s_setprio(1);
        #pragma unroll
        for (int mf = 0; mf < 4; ++mf) {
            f32x4 s = (f32x4){0.f, 0.f, 0.f, 0.f};
            #pragma unroll
            for (int kc = 0; kc < 4; ++kc) {
                int rk = mf * 16 + (l & 15);
                bf16x8 a = *(const bf16x8*)(Ka[cur] + rk * 256 +
                              ((kc * 64 + (l >> 4) * 16) ^ ((rk & 15) << 4)));
                s = __builtin_amdgcn_mfma_f32_16x16x32_bf16(a, qf[kc], s, 0, 0, 0);
            }
            st[mf] = s;
        }
        __builtin_amdgcn_s_setprio(0);

        float pm = -1e30f;
        #pragma unroll
        for (int mf = 0; mf < 4; ++mf)
            #pragma unroll
            for (int j = 0; j < 4; ++j) {
                int kv = kv0 + mf * 16 + (l >> 4) * 4 + j;
                float v = (kv <= qrow) ? st[mf][j] * scale : -1e30f;
                st[mf][j] = v;
                pm = fmaxf(pm, v);
            }
        pm = fmaxf(pm, __shfl_xor(pm, 16));
        pm = fmaxf(pm, __shfl_xor(pm, 32));
        float mn   = fmaxf(mrun, pm);
        float corr = __expf(mrun - mn);
        float ls = 0.f;
        #pragma unroll
        for (int mf = 0; mf < 4; ++mf)
            #pragma unroll
            for (int j = 0; j < 4; ++j) {
                float p = __expf(st[mf][j] - mn);
                st[mf][j] = p;
                ls += p;
            }
        ls += __shfl_xor(ls, 16);
        ls += __shfl_xor(ls, 32);
        lrun = lrun * corr + ls;
        mrun = mn;

        f32x4 cv;
        #pragma unroll
        for (int r = 0; r < 4; ++r) cv[r] = __shfl(corr, (l >> 4) * 4 + r, 64);
        #pragma unroll
        for (int nf = 0; nf < 8; ++nf) o[nf] *= cv;

        #pragma unroll
        for (int mf = 0; mf < 4; ++mf)
            #pragma unroll
            for (int r = 0; r < 4; r += 2) {
                int kv = mf * 16 + (l >> 4) * 4 + r;
                unsigned pk = (unsigned)bbits((bf16)st[mf][r]) |
                              ((unsigned)bbits((bf16)st[mf][r + 1]) << 16);
                *(unsigned*)(Pw + (l & 15) * 128 + ((kv * 2) ^ ((l & 15 & 7) << 4))) = pk;
            }

        __builtin_amdgcn_s_setprio(1);
        #pragma unroll
        for (int kc = 0; kc < 2; ++kc) {
            bf16x8 pa = *(const bf16x8*)(Pw + (l & 15) * 128 +
                           ((kc * 64 + (l >> 4) * 16) ^ ((l & 7) << 4)));
            #pragma unroll
            for (int nf = 0; nf < 8; ++nf) {
                int dr = nf * 16 + (l & 15);
                bf16x8 vb = *(const bf16x8*)(Va[cur] + dr * 128 +
                               ((kc * 64 + (l >> 4) * 16) ^ ((dr & 7) << 4)));
                o[nf] = __builtin_amdgcn_mfma_f32_16x16x32_bf16(pa, vb, o[nf], 0, 0, 0);
            }
        }
        __builtin_amdgcn_s_setprio(0);

        asm volatile("s_waitcnt vmcnt(0) lgkmcnt(0)" ::: "memory");
        __builtin_amdgcn_s_barrier();
    }
#undef ASTAGE

    float il = 1.0f / lrun;
    f32x4 iv;
    #pragma unroll
    for (int r = 0; r < 4; ++r) iv[r] = __shfl(il, (l >> 4) * 4 + r, 64);
    #pragma unroll
    for (int nf = 0; nf < 8; ++nf)
        #pragma unroll
        for (int r = 0; r < 4; ++r) {
            int row = qw + (l >> 4) * 4 + r;
            attn[(size_t)row * HID + head * HD + nf * 16 + (l & 15)] = (bf16)(o[nf][r] * iv[r]);
        }
}

extern "C" void kernel_launch(void* const* d_in, const int* in_sizes, int n_in,
                              void* d_out, int out_size, void* d_ws, size_t ws_size,
                              hipStream_t stream) {
    const float* hidden  = (const float*)d_in[0];
    const int*   pos_ids = (const int*)d_in[1];
    const float* W_qkv   = (const float*)d_in[2];
    const float* W_o     = (const float*)d_in[3];
    float*       out     = (float*)d_out;
    char*        ws      = (char*)d_ws;

    // phase-1 layout
    bf16*   Wqkv_t   = (bf16*)(ws);                 // [12288][4096] bf16 = 100663296 B
    bf16*   qkv_b    = (bf16*)(ws + 100663296);     // [2048][12288] bf16 =  50331648 B
    bf16*   hidden_b = (bf16*)(ws + 150994944);     // [2048][4096]  bf16 =  16777216 B
    float2* tab      = (float2*)(ws + 150994944);   // reuses hidden_b slot AFTER gemm1
    // phase-2 layout (aliases Wqkv_t region, dead after GEMM1)
    bf16* Qb     = (bf16*)(ws);                     // [32][2048][128] 16 MB
    bf16* Kb     = (bf16*)(ws + 16777216);          // 16 MB
    bf16* Vtb    = (bf16*)(ws + 33554432);          // [32][128][2048] 16 MB
    bf16* attn_b = (bf16*)(ws + 50331648);          // [2048][4096] 16 MB
    bf16* Wo_t   = (bf16*)(ws + 67108864);          // [4096][4096] 32 MB

    cast_flat<<<SEQ * HID / 8 / 256, 256, 0, stream>>>(hidden, hidden_b, SEQ * HID / 8);
    cast_transpose<<<dim3(QKVN / 64, HID / 64), 256, 0, stream>>>(W_qkv, Wqkv_t, HID, QKVN);
    gemm192<<<(QKVN / 192) * (SEQ / 256), 512, 0, stream>>>(hidden_b, Wqkv_t, qkv_b,
                                                            SEQ, QKVN, HID);
    rope_table<<<SEQ * 64 / 256, 256, 0, stream>>>(pos_ids, tab);
    rope_repack<<<SEQ * NHEAD * 16 / 256, 256, 0, stream>>>(qkv_b, tab, Qb, Kb);
    v_transpose<<<dim3(SEQ / 64, NHEAD), 256, 0, stream>>>(qkv_b, Vtb);
    cast_transpose<<<dim3(HID / 64, HID / 64), 256, 0, stream>>>(W_o, Wo_t, HID, HID);
    attn_mfma<<<dim3(NHEAD, SEQ / 64), 256, 0, stream>>>(Qb, Kb, Vtb, attn_b);
    gemm2p<0><<<(HID / 128) * (SEQ / 256), 512, 0, stream>>>(attn_b, Wo_t, out,
                                                             SEQ, HID, HID);
}

// Round 11
// 438.341 us; speedup vs baseline: 1.1093x; 1.1093x over previous
//
#include <hip/hip_runtime.h>
#include <hip/hip_bf16.h>
#include <math.h>

#define SEQ   2048
#define HID   4096
#define NHEAD 32
#define HD    128
#define QKVN  12288

typedef __bf16 bf16;
typedef __bf16 bf16x8 __attribute__((ext_vector_type(8)));
typedef __bf16 bf16x4 __attribute__((ext_vector_type(4)));
typedef float  f32x4  __attribute__((ext_vector_type(4)));

#define AS1 __attribute__((address_space(1)))
#define AS3 __attribute__((address_space(3)))

__device__ __forceinline__ void gload16(const void* g, void* l) {
    __builtin_amdgcn_global_load_lds((const AS1 void*)g, (AS3 void*)l, 16, 0, 0);
}

__device__ __forceinline__ unsigned short bbits(bf16 b) {
    union { bf16 b; unsigned short u; } x; x.b = b; return x.u;
}

// ========== 256x256 4-phase bf16 GEMM (round-9 proven; + bcol0 offset) ==========
// 8 waves, BK=64, 128KB LDS dbuf, counted-vmcnt(8) DEPTH-2 prefetch pipeline
// (round-10 lesson: depth-2 > read-ratio; gemm192's depth-1 regressed 51->33%).
// amdgpu_waves_per_eu(2,2) pins 256-VGPR budget (round-9 lesson). Fragment
// reuse across phases: 24 ds_read_b128 : 64 MFMA per wave per K-tile.
// by-chunked swizzle: by=id&7 -> A-panel L2-resident per XCD.
// bcol0: column-base offset for N-split mixed dispatch (tail-free grids).
__global__ __launch_bounds__(512) __attribute__((amdgpu_waves_per_eu(2, 2)))
void gemm256(const bf16* __restrict__ A, const bf16* __restrict__ Bt,
             bf16* __restrict__ C, int M, int N, int K, int bcol0) {
    __shared__ __attribute__((aligned(16))) char lds[131072];
    const int tid  = threadIdx.x;
    const int l    = tid & 63;
    const int wave = tid >> 6;      // 0..7
    const int wr   = wave >> 2;     // 0..1
    const int wc   = wave & 3;      // 0..3
    const int lh   = l >> 4;        // 0..3
    const int ll   = l & 15;
    const int by   = blockIdx.x & 7, bx = blockIdx.x >> 3;
    const int brow = by * 256, bcol = bcol0 + bx * 256;

    f32x4 acc[4][4][2];             // [quad=mh*2+nh][f][g]
    #pragma unroll
    for (int q = 0; q < 4; ++q)
        #pragma unroll
        for (int f = 0; f < 4; ++f)
            #pragma unroll
            for (int g = 0; g < 2; ++g) acc[q][f][g] = (f32x4){0.f, 0.f, 0.f, 0.f};

    const int trow = tid >> 3, tslot = tid & 7;
    const int srcs = (tslot ^ (trow & 7)) * 16;
    const size_t rowb = (size_t)K * 2;
    const char* pA[2][2]; const char* pB[2][2];
    #pragma unroll
    for (int h = 0; h < 2; ++h)
        #pragma unroll
        for (int i = 0; i < 2; ++i) {
            pA[h][i] = (const char*)A  + (size_t)(brow + h*128 + i*64 + trow) * rowb + srcs;
            pB[h][i] = (const char*)Bt + (size_t)(bcol + h*128 + i*64 + trow) * rowb + srcs;
        }

#define SA(buf, h) do { \
        gload16(pA[h][0], lds + (buf)*65536 + (h)*16384 + tid*16); \
        gload16(pA[h][1], lds + (buf)*65536 + (h)*16384 + 8192 + tid*16); \
        pA[h][0] += 128; pA[h][1] += 128; \
    } while (0)
#define SB(buf, h) do { \
        gload16(pB[h][0], lds + (buf)*65536 + 32768 + (h)*16384 + tid*16); \
        gload16(pB[h][1], lds + (buf)*65536 + 32768 + (h)*16384 + 8192 + tid*16); \
        pB[h][0] += 128; pB[h][1] += 128; \
    } while (0)

    const int sw0 = ((0 + lh) ^ (ll & 7)) << 4;
    const int sw1 = ((4 + lh) ^ (ll & 7)) << 4;

    bf16x8 af[4][2], bv0[2][2], bv1[2][2];

#define LOADA(Xb, mh) do { \
        const char* LA_ = lds + (Xb)*65536 + (mh)*16384 + (wr*64 + ll)*128; \
        _Pragma("unroll") \
        for (int f_ = 0; f_ < 4; ++f_) { \
            af[f_][0] = *(const bf16x8*)(LA_ + f_*2048 + sw0); \
            af[f_][1] = *(const bf16x8*)(LA_ + f_*2048 + sw1); \
        } \
    } while (0)
#define LOADB(Xb, nh, bvv) do { \
        const char* LB_ = lds + (Xb)*65536 + 32768 + (nh)*16384 + (wc*32 + ll)*128; \
        _Pragma("unroll") \
        for (int g_ = 0; g_ < 2; ++g_) { \
            bvv[g_][0] = *(const bf16x8*)(LB_ + g_*2048 + sw0); \
            bvv[g_][1] = *(const bf16x8*)(LB_ + g_*2048 + sw1); \
        } \
    } while (0)
#define FENCE_MMA(WAITSTR, q, bvv) do { \
        asm volatile(WAITSTR ::: "memory"); \
        __builtin_amdgcn_s_barrier(); \
        asm volatile("s_waitcnt lgkmcnt(0)" ::: "memory"); \
        __builtin_amdgcn_sched_barrier(0); \
        __builtin_amdgcn_s_setprio(1); \
        _Pragma("unroll") \
        for (int f_ = 0; f_ < 4; ++f_) \
            _Pragma("unroll") \
            for (int g_ = 0; g_ < 2; ++g_) { \
                acc[q][f_][g_] = __builtin_amdgcn_mfma_f32_16x16x32_bf16( \
                    af[f_][0], bvv[g_][0], acc[q][f_][g_], 0, 0, 0); \
                acc[q][f_][g_] = __builtin_amdgcn_mfma_f32_16x16x32_bf16( \
                    af[f_][1], bvv[g_][1], acc[q][f_][g_], 0, 0, 0); \
            } \
        __builtin_amdgcn_s_setprio(0); \
        __builtin_amdgcn_s_barrier(); \
    } while (0)

    SA(0, 0); SB(0, 0); SB(0, 1); SA(0, 1); SA(1, 0); SB(1, 0);
    asm volatile("s_waitcnt vmcnt(8)" ::: "memory");
    __builtin_amdgcn_s_barrier();

    const int NT = K >> 6;
    for (int u = 0; u < NT - 1; ++u) {
        const int X = u & 1, Y = X ^ 1;
        LOADA(X, 0); LOADB(X, 0, bv0); SB(Y, 1);
        FENCE_MMA("s_waitcnt vmcnt(8)", 0, bv0);
        LOADB(X, 1, bv1); SA(Y, 1);
        FENCE_MMA("s_waitcnt vmcnt(8)", 1, bv1);
        LOADA(X, 1);
        if (u < NT - 2) { SA(X, 0); }
        FENCE_MMA("s_waitcnt vmcnt(8)", 2, bv0);
        if (u < NT - 2) { SB(X, 0); }
        FENCE_MMA("s_waitcnt vmcnt(8)", 3, bv1);
    }
    {   // peeled last tile: drain 4 -> 2 -> 0
        const int X = (NT - 1) & 1;
        LOADA(X, 0); LOADB(X, 0, bv0);
        FENCE_MMA("s_waitcnt vmcnt(4)", 0, bv0);
        LOADB(X, 1, bv1);
        FENCE_MMA("s_waitcnt vmcnt(2)", 1, bv1);
        LOADA(X, 1);
        FENCE_MMA("s_waitcnt vmcnt(0)", 2, bv0);
        FENCE_MMA("s_nop 0", 3, bv1);
    }
#undef FENCE_MMA
#undef LOADA
#undef LOADB
#undef SA
#undef SB

    __syncthreads();
    float* ep = (float*)lds + wave * 2304;   // 64 x 36 f32 per wave
    const int c8 = (l & 3) * 8;
    #pragma unroll
    for (int q = 0; q < 4; ++q) {
        const int mh = q >> 1, nh = q & 1;
        #pragma unroll
        for (int f = 0; f < 4; ++f)
            #pragma unroll
            for (int g = 0; g < 2; ++g)
                #pragma unroll
                for (int j = 0; j < 4; ++j)
                    ep[(f*16 + lh*4 + j) * 36 + g*16 + ll] = acc[q][f][g][j];
        #pragma unroll
        for (int it = 0; it < 4; ++it) {
            int r2 = it * 16 + (l >> 2);
            const float* src = ep + r2 * 36 + c8;
            bf16x8 o;
            #pragma unroll
            for (int j = 0; j < 8; ++j) o[j] = (bf16)src[j];
            size_t grow = (size_t)(brow + mh*128 + wr*64 + r2);
            *(bf16x8*)(C + grow * N + bcol + nh*128 + wc*32 + c8) = o;
        }
    }
}

// ========== 256x128 2-phase bf16 GEMM (proven; + bcol0 offset) ==========
template<int OB>
__global__ __launch_bounds__(512, 2) void gemm2p(const bf16* __restrict__ A,
                                                 const bf16* __restrict__ Bt,
                                                 void* __restrict__ Cv,
                                                 int M, int N, int K, int bcol0) {
    __shared__ __attribute__((aligned(16))) char lds[98304];
    const int tid  = threadIdx.x;
    const int l    = tid & 63;
    const int wave = tid >> 6;
    const int wr   = wave >> 2;
    const int wc   = wave & 3;
    const int lh   = l >> 4;
    const int ll   = l & 15;

    const int by   = blockIdx.x & 7;
    const int bx   = blockIdx.x >> 3;
    const int brow = by * 256, bcol = bcol0 + bx * 128;

    f32x4 acc[2][4][2];
    #pragma unroll
    for (int m = 0; m < 2; ++m)
        #pragma unroll
        for (int f = 0; f < 4; ++f)
            #pragma unroll
            for (int g = 0; g < 2; ++g) acc[m][f][g] = (f32x4){0.f, 0.f, 0.f, 0.f};

    const int trow = tid >> 3, tslot = tid & 7;
    const int srcs = (tslot ^ (trow & 7)) * 16;
    const size_t rowb = (size_t)K * 2;
    const char* pA[2][2]; const char* pB[2];
    #pragma unroll
    for (int h = 0; h < 2; ++h)
        #pragma unroll
        for (int i = 0; i < 2; ++i)
            pA[h][i] = (const char*)A + (size_t)(brow + h*128 + i*64 + trow) * rowb + srcs;
    #pragma unroll
    for (int i = 0; i < 2; ++i)
        pB[i] = (const char*)Bt + (size_t)(bcol + i*64 + trow) * rowb + srcs;

#define SA(buf, h) do { \
        gload16(pA[h][0], lds + (buf)*32768 + (h)*16384 + tid*16); \
        gload16(pA[h][1], lds + (buf)*32768 + (h)*16384 + 8192 + tid*16); \
        pA[h][0] += 128; pA[h][1] += 128; \
    } while (0)
#define SB(buf) do { \
        gload16(pB[0], lds + 65536 + (buf)*16384 + tid*16); \
        gload16(pB[1], lds + 65536 + (buf)*16384 + 8192 + tid*16); \
        pB[0] += 128; pB[1] += 128; \
    } while (0)

    const int sw0 = ((0 + lh) ^ (ll & 7)) << 4;
    const int sw1 = ((4 + lh) ^ (ll & 7)) << 4;

#define PHASE(Xb, mh, STAGE_STMT, WAITSTR) do { \
        const char* LA_ = lds + (Xb)*32768 + (mh)*16384 + (wr*64 + ll)*128; \
        const char* LB_ = lds + 65536 + (Xb)*16384 + (wc*32 + ll)*128; \
        bf16x8 af_[4][2], bv_[2][2]; \
        _Pragma("unroll") \
        for (int f_ = 0; f_ < 4; ++f_) { \
            af_[f_][0] = *(const bf16x8*)(LA_ + f_*2048 + sw0); \
            af_[f_][1] = *(const bf16x8*)(LA_ + f_*2048 + sw1); \
        } \
        _Pragma("unroll") \
        for (int g_ = 0; g_ < 2; ++g_) { \
            bv_[g_][0] = *(const bf16x8*)(LB_ + g_*2048 + sw0); \
            bv_[g_][1] = *(const bf16x8*)(LB_ + g_*2048 + sw1); \
        } \
        STAGE_STMT; \
        asm volatile(WAITSTR ::: "memory"); \
        __builtin_amdgcn_s_barrier(); \
        asm volatile("s_waitcnt lgkmcnt(0)" ::: "memory"); \
        __builtin_amdgcn_sched_barrier(0); \
        __builtin_amdgcn_s_setprio(1); \
        _Pragma("unroll") \
        for (int f_ = 0; f_ < 4; ++f_) \
            _Pragma("unroll") \
            for (int g_ = 0; g_ < 2; ++g_) { \
                acc[mh][f_][g_] = __builtin_amdgcn_mfma_f32_16x16x32_bf16( \
                    af_[f_][0], bv_[g_][0], acc[mh][f_][g_], 0, 0, 0); \
                acc[mh][f_][g_] = __builtin_amdgcn_mfma_f32_16x16x32_bf16( \
                    af_[f_][1], bv_[g_][1], acc[mh][f_][g_], 0, 0, 0); \
            } \
        __builtin_amdgcn_s_setprio(0); \
        __builtin_amdgcn_s_barrier(); \
    } while (0)

    SA(0, 0); SB(0); SA(0, 1); SA(1, 0);
    asm volatile("s_waitcnt vmcnt(4)" ::: "memory");
    __builtin_amdgcn_s_barrier();

    const int NT = K >> 6;
    for (int u = 0; u < NT - 2; ++u) {
        const int X = u & 1, Y = X ^ 1;
        PHASE(X, 0, SB(Y), "s_waitcnt vmcnt(4)");
        PHASE(X, 1, { SA(Y, 1); SA(X, 0); }, "s_waitcnt vmcnt(4)");
    }
    {
        const int X = (NT - 2) & 1, Y = X ^ 1;
        PHASE(X, 0, SB(Y), "s_waitcnt vmcnt(4)");
        PHASE(X, 1, SA(Y, 1), "s_waitcnt vmcnt(2)");
    }
    {
        const int X = (NT - 1) & 1;
        PHASE(X, 0, ((void)0), "s_waitcnt vmcnt(0)");
        PHASE(X, 1, ((void)0), "s_nop 0");
    }
#undef PHASE
#undef SA
#undef SB

    __syncthreads();
    float* ep = (float*)lds + wave * 2304;
    const int cq = l & 3;
    #pragma unroll
    for (int mh = 0; mh < 2; ++mh) {
        #pragma unroll
        for (int f = 0; f < 4; ++f)
            #pragma unroll
            for (int g = 0; g < 2; ++g)
                #pragma unroll
                for (int j = 0; j < 4; ++j)
                    ep[(f*16 + lh*4 + j) * 36 + g*16 + ll] = acc[mh][f][g][j];
        #pragma unroll
        for (int it = 0; it < 4; ++it) {
            int r2 = it * 16 + (l >> 2);
            const float* src = ep + r2 * 36 + cq * 8;
            size_t grow = (size_t)(brow + mh*128 + wr*64 + r2);
            int gcol = bcol + wc*32 + cq*8;
            if (OB == 0) {
                float* dst = (float*)Cv + grow * N + gcol;
                *(f32x4*)dst       = *(const f32x4*)src;
                *(f32x4*)(dst + 4) = *(const f32x4*)(src + 4);
            } else {
                bf16x8 o;
                #pragma unroll
                for (int jj = 0; jj < 8; ++jj) o[jj] = (bf16)src[jj];
                *(bf16x8*)((bf16*)Cv + grow * N + gcol) = o;
            }
        }
    }
}

// ---------------- f32 -> bf16 flat cast (8/thread) ----------------
__global__ __launch_bounds__(256) void cast_flat(const float* __restrict__ in,
                                                 bf16* __restrict__ out, int n8) {
    int i = blockIdx.x * 256 + threadIdx.x;
    if (i >= n8) return;
    float4 a = ((const float4*)in)[2 * i];
    float4 b = ((const float4*)in)[2 * i + 1];
    bf16x8 o = {(bf16)a.x, (bf16)a.y, (bf16)a.z, (bf16)a.w,
                (bf16)b.x, (bf16)b.y, (bf16)b.z, (bf16)b.w};
    *(bf16x8*)(out + (size_t)i * 8) = o;
}

// ---------------- f32 [R][C] -> bf16 [C][R] transpose-cast ----------------
__global__ __launch_bounds__(256) void cast_transpose(const float* __restrict__ in,
                                                      bf16* __restrict__ out, int R, int C) {
    __shared__ float t[64][65];
    const int r0 = blockIdx.y * 64, c0 = blockIdx.x * 64;
    #pragma unroll
    for (int i = 0; i < 4; ++i) {
        int idx = i * 256 + threadIdx.x;
        int rr = idx >> 4, c4 = (idx & 15) * 4;
        float4 v = *(const float4*)&in[(size_t)(r0 + rr) * C + c0 + c4];
        t[rr][c4] = v.x; t[rr][c4 + 1] = v.y; t[rr][c4 + 2] = v.z; t[rr][c4 + 3] = v.w;
    }
    __syncthreads();
    #pragma unroll
    for (int i = 0; i < 2; ++i) {
        int idx = i * 256 + threadIdx.x;
        int rr = idx >> 3, c8 = (idx & 7) * 8;
        bf16x8 o;
        #pragma unroll
        for (int j = 0; j < 8; ++j) o[j] = (bf16)t[c8 + j][rr];
        *(bf16x8*)&out[(size_t)(c0 + rr) * R + r0 + c8] = o;
    }
}

// ---------------- RoPE trig table ----------------
__global__ __launch_bounds__(256) void rope_table(const int* __restrict__ pos_ids,
                                                  float2* __restrict__ tab) {
    int id = blockIdx.x * 256 + threadIdx.x;   // SEQ*64
    int s = id >> 6, d = id & 63;
    float pos = (float)pos_ids[s];
    float inv = expf(-9.210340371976184f * ((float)d * (1.0f / 64.0f)));
    float sn, cs;
    sincosf(pos * inv, &sn, &cs);
    tab[id] = make_float2(cs, sn);
}

// ---------------- RoPE (NeoX) + repack q,k -> [head][seq][hd] ----------------
__global__ __launch_bounds__(256) void rope_repack(const bf16* __restrict__ qkv,
                                                   const float2* __restrict__ tab,
                                                   bf16* __restrict__ Qb,
                                                   bf16* __restrict__ Kb) {
    int id = blockIdx.x * 256 + threadIdx.x;   // SEQ*NHEAD*16
    const int d4 = (id & 15) * 4;
    const int h  = (id >> 4) & (NHEAD - 1);
    const int s  = id >> 9;

    float2 tr[4];
    #pragma unroll
    for (int i = 0; i < 4; ++i) tr[i] = tab[s * 64 + d4 + i];

    const bf16* row = qkv + (size_t)s * QKVN;
    {
        bf16x4 lo = *(const bf16x4*)(row + h * HD + d4);
        bf16x4 hi = *(const bf16x4*)(row + h * HD + 64 + d4);
        bf16x4 olo, ohi;
        #pragma unroll
        for (int i = 0; i < 4; ++i) {
            float x1 = (float)lo[i], x2 = (float)hi[i];
            olo[i] = (bf16)(x1 * tr[i].x - x2 * tr[i].y);
            ohi[i] = (bf16)(x2 * tr[i].x + x1 * tr[i].y);
        }
        bf16* qo = Qb + ((size_t)h * SEQ + s) * HD;
        *(bf16x4*)(qo + d4) = olo;
        *(bf16x4*)(qo + 64 + d4) = ohi;
    }
    {
        bf16x4 lo = *(const bf16x4*)(row + HID + h * HD + d4);
        bf16x4 hi = *(const bf16x4*)(row + HID + h * HD + 64 + d4);
        bf16x4 olo, ohi;
        #pragma unroll
        for (int i = 0; i < 4; ++i) {
            float x1 = (float)lo[i], x2 = (float)hi[i];
            olo[i] = (bf16)(x1 * tr[i].x - x2 * tr[i].y);
            ohi[i] = (bf16)(x2 * tr[i].x + x1 * tr[i].y);
        }
        bf16* ko = Kb + ((size_t)h * SEQ + s) * HD;
        *(bf16x4*)(ko + d4) = olo;
        *(bf16x4*)(ko + 64 + d4) = ohi;
    }
}

// ---------------- V transpose: qkv v-slice -> Vt [head][hd][seq] ----------------
__global__ __launch_bounds__(256) void v_transpose(const bf16* __restrict__ qkv,
                                                   bf16* __restrict__ Vt) {
    __shared__ bf16 t[64][130];
    const int h = blockIdx.y, s0 = blockIdx.x * 64;
    #pragma unroll
    for (int i = 0; i < 4; ++i) {
        int idx = i * 256 + threadIdx.x;
        int ss = idx >> 4, c8 = (idx & 15) * 8;
        bf16x8 v = *(const bf16x8*)&qkv[(size_t)(s0 + ss) * QKVN + 2 * HID + h * HD + c8];
        #pragma unroll
        for (int j = 0; j < 8; ++j) t[ss][c8 + j] = v[j];
    }
    __syncthreads();
    #pragma unroll
    for (int i = 0; i < 4; ++i) {
        int idx = i * 256 + threadIdx.x;
        int dd = idx >> 3, s8 = (idx & 7) * 8;
        bf16x8 o;
        #pragma unroll
        for (int j = 0; j < 8; ++j) o[j] = t[s8 + j][dd];
        *(bf16x8*)&Vt[((size_t)h * HD + dd) * SEQ + s0 + s8] = o;
    }
}

// ---------------- bf16 MFMA causal flash attention, 2-phase K/V dbuf ----------------
__global__ __launch_bounds__(256) void attn_mfma(const bf16* __restrict__ Qb,
                                                 const bf16* __restrict__ Kb,
                                                 const bf16* __restrict__ Vt,
                                                 bf16* __restrict__ attn) {
    __shared__ __attribute__((aligned(16))) char Ka[2][16384];
    __shared__ __attribute__((aligned(16))) char Va[2][16384];
    __shared__ __attribute__((aligned(16))) char Ps[4 * 2048];
    const int tid  = threadIdx.x, l = tid & 63, wave = tid >> 6;
    const int head = blockIdx.x;
    const int qb   = gridDim.y - 1 - blockIdx.y;
    const int q0   = qb * 64;
    const int qw   = q0 + wave * 16;
    const float scale = 0.08838834764831845f;

    bf16x8 qf[4];
    const bf16* Qg = Qb + ((size_t)head * SEQ + qw + (l & 15)) * HD;
    #pragma unroll
    for (int kc = 0; kc < 4; ++kc) qf[kc] = *(const bf16x8*)(Qg + kc * 32 + (l >> 4) * 8);

    f32x4 o[8];
    #pragma unroll
    for (int i = 0; i < 8; ++i) o[i] = (f32x4){0.f, 0.f, 0.f, 0.f};
    float mrun = -1e30f, lrun = 0.f;
    const int qrow  = qw + (l & 15);
    const int ntile = qb + 1;

    const char* Kg = (const char*)(Kb + (size_t)head * SEQ * HD);
    const char* Vg = (const char*)(Vt + (size_t)head * HD * SEQ);
    char* Pw = Ps + wave * 2048;

#define ASTAGE(b, t0) do { \
        const int kv0_ = (t0) * 64; \
        _Pragma("unroll") \
        for (int i = 0; i < 4; ++i) { \
            int c = i * 256 + tid; \
            int rk_ = c >> 4, slk_ = c & 15; \
            gload16(Kg + (size_t)(kv0_ + rk_) * 256 + ((slk_ * 16) ^ ((rk_ & 15) << 4)), \
                    Ka[b] + (size_t)(i * 256 + (tid & 192)) * 16); \
            int rv_ = c >> 3, slv_ = c & 7; \
            gload16(Vg + (size_t)rv_ * (SEQ * 2) + (size_t)kv0_ * 2 + ((slv_ * 16) ^ ((rv_ & 7) << 4)), \
                    Va[b] + (size_t)(i * 256 + (tid & 192)) * 16); \
        } \
    } while (0)

    ASTAGE(0, 0);
    asm volatile("s_waitcnt vmcnt(0)" ::: "memory");
    __builtin_amdgcn_s_barrier();

    for (int t = 0; t < ntile; ++t) {
        const int cur = t & 1;
        const int kv0 = t * 64;
        if (t + 1 < ntile) ASTAGE(cur ^ 1, t + 1);

        f32x4 st[4];
        __builtin_amdgcn_s_setprio(1);
        #pragma unroll
        for (int mf = 0; mf < 4; ++mf) {
            f32x4 s = (f32x4){0.f, 0.f, 0.f, 0.f};
            #pragma unroll
            for (int kc = 0; kc < 4; ++kc) {
                int rk = mf * 16 + (l & 15);
                bf16x8 a = *(const bf16x8*)(Ka[cur] + rk * 256 +
                              ((kc * 64 + (l >> 4) * 16) ^ ((rk & 15) << 4)));
                s = __builtin_amdgcn_mfma_f32_16x16x32_bf16(a, qf[kc], s, 0, 0, 0);
            }
            st[mf] = s;
        }
        __builtin_amdgcn_s_setprio(0);

        float pm = -1e30f;
        #pragma unroll
        for (int mf = 0; mf < 4; ++mf)
            #pragma unroll
            for (int j = 0; j < 4; ++j) {
                int kv = kv0 + mf * 16 + (l >> 4) * 4 + j;
                float v = (kv <= qrow) ? st[mf][j] * scale : -1e30f;
                st[mf][j] = v;
                pm = fmaxf(pm, v);
            }
        pm = fmaxf(pm, __shfl_xor(pm, 16));
        pm = fmaxf(pm, __shfl_xor(pm, 32));
        float mn   = fmaxf(mrun, pm);
        float corr = __expf(mrun - mn);
        float ls = 0.f;
        #pragma unroll
        for (int mf = 0; mf < 4; ++mf)
            #pragma unroll
            for (int j = 0; j < 4; ++j) {
                float p = __expf(st[mf][j] - mn);
                st[mf][j] = p;
                ls += p;
            }
        ls += __shfl_xor(ls, 16);
        ls += __shfl_xor(ls, 32);
        lrun = lrun * corr + ls;
        mrun = mn;

        f32x4 cv;
        #pragma unroll
        for (int r = 0; r < 4; ++r) cv[r] = __shfl(corr, (l >> 4) * 4 + r, 64);
        #pragma unroll
        for (int nf = 0; nf < 8; ++nf) o[nf] *= cv;

        #pragma unroll
        for (int mf = 0; mf < 4; ++mf)
            #pragma unroll
            for (int r = 0; r < 4; r += 2) {
                int kv = mf * 16 + (l >> 4) * 4 + r;
                unsigned pk = (unsigned)bbits((bf16)st[mf][r]) |
                              ((unsigned)bbits((bf16)st[mf][r + 1]) << 16);
                *(unsigned*)(Pw + (l & 15) * 128 + ((kv * 2) ^ ((l & 15 & 7) << 4))) = pk;
            }

        __builtin_amdgcn_s_setprio(1);
        #pragma unroll
        for (int kc = 0; kc < 2; ++kc) {
            bf16x8 pa = *(const bf16x8*)(Pw + (l & 15) * 128 +
                           ((kc * 64 + (l >> 4) * 16) ^ ((l & 7) << 4)));
            #pragma unroll
            for (int nf = 0; nf < 8; ++nf) {
                int dr = nf * 16 + (l & 15);
                bf16x8 vb = *(const bf16x8*)(Va[cur] + dr * 128 +
                               ((kc * 64 + (l >> 4) * 16) ^ ((dr & 7) << 4)));
                o[nf] = __builtin_amdgcn_mfma_f32_16x16x32_bf16(pa, vb, o[nf], 0, 0, 0);
            }
        }
        __builtin_amdgcn_s_setprio(0);

        asm volatile("s_waitcnt vmcnt(0) lgkmcnt(0)" ::: "memory");
        __builtin_amdgcn_s_barrier();
    }
#undef ASTAGE

    float il = 1.0f / lrun;
    f32x4 iv;
    #pragma unroll
    for (int r = 0; r < 4; ++r) iv[r] = __shfl(il, (l >> 4) * 4 + r, 64);
    #pragma unroll
    for (int nf = 0; nf < 8; ++nf)
        #pragma unroll
        for (int r = 0; r < 4; ++r) {
            int row = qw + (l >> 4) * 4 + r;
            attn[(size_t)row * HID + head * HD + nf * 16 + (l & 15)] = (bf16)(o[nf][r] * iv[r]);
        }
}

extern "C" void kernel_launch(void* const* d_in, const int* in_sizes, int n_in,
                              void* d_out, int out_size, void* d_ws, size_t ws_size,
                              hipStream_t stream) {
    const float* hidden  = (const float*)d_in[0];
    const int*   pos_ids = (const int*)d_in[1];
    const float* W_qkv   = (const float*)d_in[2];
    const float* W_o     = (const float*)d_in[3];
    float*       out     = (float*)d_out;
    char*        ws      = (char*)d_ws;

    // phase-1 layout
    bf16*   Wqkv_t   = (bf16*)(ws);                 // [12288][4096] bf16 = 100663296 B
    bf16*   qkv_b    = (bf16*)(ws + 100663296);     // [2048][12288] bf16 =  50331648 B
    bf16*   hidden_b = (bf16*)(ws + 150994944);     // [2048][4096]  bf16 =  16777216 B
    float2* tab      = (float2*)(ws + 150994944);   // reuses hidden_b slot AFTER gemm1
    // phase-2 layout (aliases Wqkv_t region, dead after GEMM1)
    bf16* Qb     = (bf16*)(ws);                     // [32][2048][128] 16 MB
    bf16* Kb     = (bf16*)(ws + 16777216);          // 16 MB
    bf16* Vtb    = (bf16*)(ws + 33554432);          // [32][128][2048] 16 MB
    bf16* attn_b = (bf16*)(ws + 50331648);          // [2048][4096] 16 MB
    bf16* Wo_t   = (bf16*)(ws + 67108864);          // [4096][4096] 32 MB

    cast_flat<<<SEQ * HID / 8 / 256, 256, 0, stream>>>(hidden, hidden_b, SEQ * HID / 8);
    cast_transpose<<<dim3(QKVN / 64, HID / 64), 256, 0, stream>>>(W_qkv, Wqkv_t, HID, QKVN);
    // GEMM1, N-split for tail-free grids: cols 0..8191 via 256x256 (256 blocks =
    // 1 round @ 51% steady), cols 8192..12287 via 256x128 (256 blocks = 1 round).
    gemm256<<<(8192 / 256) * (SEQ / 256), 512, 0, stream>>>(hidden_b, Wqkv_t, qkv_b,
                                                            SEQ, QKVN, HID, 0);
    gemm2p<1><<<(4096 / 128) * (SEQ / 256), 512, 0, stream>>>(hidden_b, Wqkv_t, qkv_b,
                                                              SEQ, QKVN, HID, 8192);
    rope_table<<<SEQ * 64 / 256, 256, 0, stream>>>(pos_ids, tab);
    rope_repack<<<SEQ * NHEAD * 16 / 256, 256, 0, stream>>>(qkv_b, tab, Qb, Kb);
    v_transpose<<<dim3(SEQ / 64, NHEAD), 256, 0, stream>>>(qkv_b, Vtb);
    cast_transpose<<<dim3(HID / 64, HID / 64), 256, 0, stream>>>(W_o, Wo_t, HID, HID);
    attn_mfma<<<dim3(NHEAD, SEQ / 64), 256, 0, stream>>>(Qb, Kb, Vtb, attn_b);
    gemm2p<0><<<(HID / 128) * (SEQ / 256), 512, 0, stream>>>(attn_b, Wo_t, out,
                                                             SEQ, HID, HID, 0);
}

// Round 12
// 424.544 us; speedup vs baseline: 1.1453x; 1.0325x over previous
//
#include <hip/hip_runtime.h>
#include <hip/hip_bf16.h>
#include <math.h>

#define SEQ   2048
#define HID   4096
#define NHEAD 32
#define HD    128
#define QKVN  12288

typedef __bf16 bf16;
typedef __bf16 bf16x8 __attribute__((ext_vector_type(8)));
typedef __bf16 bf16x4 __attribute__((ext_vector_type(4)));
typedef float  f32x4  __attribute__((ext_vector_type(4)));

#define AS1 __attribute__((address_space(1)))
#define AS3 __attribute__((address_space(3)))

__device__ __forceinline__ void gload16(const void* g, void* l) {
    __builtin_amdgcn_global_load_lds((const AS1 void*)g, (AS3 void*)l, 16, 0, 0);
}

__device__ __forceinline__ unsigned short bbits(bf16 b) {
    union { bf16 b; unsigned short u; } x; x.b = b; return x.u;
}

// ========== 256x256 4-phase bf16 GEMM (round-9/11 proven) ==========
__global__ __launch_bounds__(512) __attribute__((amdgpu_waves_per_eu(2, 2)))
void gemm256(const bf16* __restrict__ A, const bf16* __restrict__ Bt,
             bf16* __restrict__ C, int M, int N, int K, int bcol0) {
    __shared__ __attribute__((aligned(16))) char lds[131072];
    const int tid  = threadIdx.x;
    const int l    = tid & 63;
    const int wave = tid >> 6;      // 0..7
    const int wr   = wave >> 2;     // 0..1
    const int wc   = wave & 3;      // 0..3
    const int lh   = l >> 4;        // 0..3
    const int ll   = l & 15;
    const int by   = blockIdx.x & 7, bx = blockIdx.x >> 3;
    const int brow = by * 256, bcol = bcol0 + bx * 256;

    f32x4 acc[4][4][2];             // [quad=mh*2+nh][f][g]
    #pragma unroll
    for (int q = 0; q < 4; ++q)
        #pragma unroll
        for (int f = 0; f < 4; ++f)
            #pragma unroll
            for (int g = 0; g < 2; ++g) acc[q][f][g] = (f32x4){0.f, 0.f, 0.f, 0.f};

    const int trow = tid >> 3, tslot = tid & 7;
    const int srcs = (tslot ^ (trow & 7)) * 16;
    const size_t rowb = (size_t)K * 2;
    const char* pA[2][2]; const char* pB[2][2];
    #pragma unroll
    for (int h = 0; h < 2; ++h)
        #pragma unroll
        for (int i = 0; i < 2; ++i) {
            pA[h][i] = (const char*)A  + (size_t)(brow + h*128 + i*64 + trow) * rowb + srcs;
            pB[h][i] = (const char*)Bt + (size_t)(bcol + h*128 + i*64 + trow) * rowb + srcs;
        }

#define SA(buf, h) do { \
        gload16(pA[h][0], lds + (buf)*65536 + (h)*16384 + tid*16); \
        gload16(pA[h][1], lds + (buf)*65536 + (h)*16384 + 8192 + tid*16); \
        pA[h][0] += 128; pA[h][1] += 128; \
    } while (0)
#define SB(buf, h) do { \
        gload16(pB[h][0], lds + (buf)*65536 + 32768 + (h)*16384 + tid*16); \
        gload16(pB[h][1], lds + (buf)*65536 + 32768 + (h)*16384 + 8192 + tid*16); \
        pB[h][0] += 128; pB[h][1] += 128; \
    } while (0)

    const int sw0 = ((0 + lh) ^ (ll & 7)) << 4;
    const int sw1 = ((4 + lh) ^ (ll & 7)) << 4;

    bf16x8 af[4][2], bv0[2][2], bv1[2][2];

#define LOADA(Xb, mh) do { \
        const char* LA_ = lds + (Xb)*65536 + (mh)*16384 + (wr*64 + ll)*128; \
        _Pragma("unroll") \
        for (int f_ = 0; f_ < 4; ++f_) { \
            af[f_][0] = *(const bf16x8*)(LA_ + f_*2048 + sw0); \
            af[f_][1] = *(const bf16x8*)(LA_ + f_*2048 + sw1); \
        } \
    } while (0)
#define LOADB(Xb, nh, bvv) do { \
        const char* LB_ = lds + (Xb)*65536 + 32768 + (nh)*16384 + (wc*32 + ll)*128; \
        _Pragma("unroll") \
        for (int g_ = 0; g_ < 2; ++g_) { \
            bvv[g_][0] = *(const bf16x8*)(LB_ + g_*2048 + sw0); \
            bvv[g_][1] = *(const bf16x8*)(LB_ + g_*2048 + sw1); \
        } \
    } while (0)
#define FENCE_MMA(WAITSTR, q, bvv) do { \
        asm volatile(WAITSTR ::: "memory"); \
        __builtin_amdgcn_s_barrier(); \
        asm volatile("s_waitcnt lgkmcnt(0)" ::: "memory"); \
        __builtin_amdgcn_sched_barrier(0); \
        __builtin_amdgcn_s_setprio(1); \
        _Pragma("unroll") \
        for (int f_ = 0; f_ < 4; ++f_) \
            _Pragma("unroll") \
            for (int g_ = 0; g_ < 2; ++g_) { \
                acc[q][f_][g_] = __builtin_amdgcn_mfma_f32_16x16x32_bf16( \
                    af[f_][0], bvv[g_][0], acc[q][f_][g_], 0, 0, 0); \
                acc[q][f_][g_] = __builtin_amdgcn_mfma_f32_16x16x32_bf16( \
                    af[f_][1], bvv[g_][1], acc[q][f_][g_], 0, 0, 0); \
            } \
        __builtin_amdgcn_s_setprio(0); \
        __builtin_amdgcn_s_barrier(); \
    } while (0)

    SA(0, 0); SB(0, 0); SB(0, 1); SA(0, 1); SA(1, 0); SB(1, 0);
    asm volatile("s_waitcnt vmcnt(8)" ::: "memory");
    __builtin_amdgcn_s_barrier();

    const int NT = K >> 6;
    for (int u = 0; u < NT - 1; ++u) {
        const int X = u & 1, Y = X ^ 1;
        LOADA(X, 0); LOADB(X, 0, bv0); SB(Y, 1);
        FENCE_MMA("s_waitcnt vmcnt(8)", 0, bv0);
        LOADB(X, 1, bv1); SA(Y, 1);
        FENCE_MMA("s_waitcnt vmcnt(8)", 1, bv1);
        LOADA(X, 1);
        if (u < NT - 2) { SA(X, 0); }
        FENCE_MMA("s_waitcnt vmcnt(8)", 2, bv0);
        if (u < NT - 2) { SB(X, 0); }
        FENCE_MMA("s_waitcnt vmcnt(8)", 3, bv1);
    }
    {
        const int X = (NT - 1) & 1;
        LOADA(X, 0); LOADB(X, 0, bv0);
        FENCE_MMA("s_waitcnt vmcnt(4)", 0, bv0);
        LOADB(X, 1, bv1);
        FENCE_MMA("s_waitcnt vmcnt(2)", 1, bv1);
        LOADA(X, 1);
        FENCE_MMA("s_waitcnt vmcnt(0)", 2, bv0);
        FENCE_MMA("s_nop 0", 3, bv1);
    }
#undef FENCE_MMA
#undef LOADA
#undef LOADB
#undef SA
#undef SB

    __syncthreads();
    float* ep = (float*)lds + wave * 2304;
    const int c8 = (l & 3) * 8;
    #pragma unroll
    for (int q = 0; q < 4; ++q) {
        const int mh = q >> 1, nh = q & 1;
        #pragma unroll
        for (int f = 0; f < 4; ++f)
            #pragma unroll
            for (int g = 0; g < 2; ++g)
                #pragma unroll
                for (int j = 0; j < 4; ++j)
                    ep[(f*16 + lh*4 + j) * 36 + g*16 + ll] = acc[q][f][g][j];
        #pragma unroll
        for (int it = 0; it < 4; ++it) {
            int r2 = it * 16 + (l >> 2);
            const float* src = ep + r2 * 36 + c8;
            bf16x8 o;
            #pragma unroll
            for (int j = 0; j < 8; ++j) o[j] = (bf16)src[j];
            size_t grow = (size_t)(brow + mh*128 + wr*64 + r2);
            *(bf16x8*)(C + grow * N + bcol + nh*128 + wc*32 + c8) = o;
        }
    }
}

// ========== 128x256 2-phase bf16 GEMM (tail-free for N=4096 shapes) ==========
// 16 row-tiles x (Ncols/256) col-tiles = 256 blocks for M=2048, Ncols=4096.
// 8 waves as 2(wr)x4(wc); wave-tile 64x64, acc[4][4]=64 f32 (no-spill regime).
// A-frags (8 reads) loaded at p0, reused at p1; B 2 frag-pairs per phase.
// 16 reads : 32 MFMA per tile (0.5 vs gemm2p's 0.75). Depth-2 pipeline:
// p0 stages B(next) [4 gloads], p1 stages A(next2) into dead A region [2].
// Uniform vmcnt(6); prologue SA(0),SB(0),SA(1)->vmcnt(2); peel 6->4->0.
// XCD map: id&15 = row-tile -> each XCD pins 2 A-panels (2MB) in L2.
template<int OB>
__global__ __launch_bounds__(512) __attribute__((amdgpu_waves_per_eu(2, 2)))
void gemm128n(const bf16* __restrict__ A, const bf16* __restrict__ Bt,
              void* __restrict__ Cv, int M, int N, int K, int bcol0) {
    __shared__ __attribute__((aligned(16))) char lds[98304];
    // A: [buf][128 rows][128B] at buf*16384 (32KB); B: [buf][256 rows][128B] at 32768+buf*32768
    const int tid  = threadIdx.x;
    const int l    = tid & 63;
    const int wave = tid >> 6;      // 0..7
    const int wr   = wave >> 2;     // 0..1
    const int wc   = wave & 3;      // 0..3
    const int lh   = l >> 4;        // 0..3
    const int ll   = l & 15;
    const int brow = (blockIdx.x & 15) * 128;
    const int bcol = bcol0 + (blockIdx.x >> 4) * 256;

    f32x4 acc[4][4];                // [f(row frag)][c = nh*2+g (col frag)]
    #pragma unroll
    for (int f = 0; f < 4; ++f)
        #pragma unroll
        for (int c = 0; c < 4; ++c) acc[f][c] = (f32x4){0.f, 0.f, 0.f, 0.f};

    const int trow = tid >> 3, tslot = tid & 7;
    const int srcs = (tslot ^ (trow & 7)) * 16;
    const size_t rowb = (size_t)K * 2;
    const char* pA[2]; const char* pB[4];
    #pragma unroll
    for (int i = 0; i < 2; ++i)
        pA[i] = (const char*)A + (size_t)(brow + i*64 + trow) * rowb + srcs;
    #pragma unroll
    for (int i = 0; i < 4; ++i)
        pB[i] = (const char*)Bt + (size_t)(bcol + i*64 + trow) * rowb + srcs;

#define SA(buf) do { \
        gload16(pA[0], lds + (buf)*16384 + tid*16); \
        gload16(pA[1], lds + (buf)*16384 + 8192 + tid*16); \
        pA[0] += 128; pA[1] += 128; \
    } while (0)
#define SB(buf) do { \
        gload16(pB[0], lds + 32768 + (buf)*32768 + tid*16); \
        gload16(pB[1], lds + 32768 + (buf)*32768 + 8192 + tid*16); \
        gload16(pB[2], lds + 32768 + (buf)*32768 + 16384 + tid*16); \
        gload16(pB[3], lds + 32768 + (buf)*32768 + 24576 + tid*16); \
        pB[0] += 128; pB[1] += 128; pB[2] += 128; pB[3] += 128; \
    } while (0)

    const int sw0 = ((0 + lh) ^ (ll & 7)) << 4;
    const int sw1 = ((4 + lh) ^ (ll & 7)) << 4;

    bf16x8 af[4][2];                // persists across both phases of a tile

#define LOADA(Xb) do { \
        const char* LA_ = lds + (Xb)*16384 + (wr*64 + ll)*128; \
        _Pragma("unroll") \
        for (int f_ = 0; f_ < 4; ++f_) { \
            af[f_][0] = *(const bf16x8*)(LA_ + f_*2048 + sw0); \
            af[f_][1] = *(const bf16x8*)(LA_ + f_*2048 + sw1); \
        } \
    } while (0)
#define PHASE(Xb, nh, STAGE_STMT, WAITSTR) do { \
        const char* LB_ = lds + 32768 + (Xb)*32768 + (wc*64 + (nh)*32 + ll)*128; \
        bf16x8 bv_[2][2]; \
        _Pragma("unroll") \
        for (int g_ = 0; g_ < 2; ++g_) { \
            bv_[g_][0] = *(const bf16x8*)(LB_ + g_*2048 + sw0); \
            bv_[g_][1] = *(const bf16x8*)(LB_ + g_*2048 + sw1); \
        } \
        STAGE_STMT; \
        asm volatile(WAITSTR ::: "memory"); \
        __builtin_amdgcn_s_barrier(); \
        asm volatile("s_waitcnt lgkmcnt(0)" ::: "memory"); \
        __builtin_amdgcn_sched_barrier(0); \
        __builtin_amdgcn_s_setprio(1); \
        _Pragma("unroll") \
        for (int f_ = 0; f_ < 4; ++f_) \
            _Pragma("unroll") \
            for (int g_ = 0; g_ < 2; ++g_) { \
                acc[f_][(nh)*2+g_] = __builtin_amdgcn_mfma_f32_16x16x32_bf16( \
                    af[f_][0], bv_[g_][0], acc[f_][(nh)*2+g_], 0, 0, 0); \
                acc[f_][(nh)*2+g_] = __builtin_amdgcn_mfma_f32_16x16x32_bf16( \
                    af[f_][1], bv_[g_][1], acc[f_][(nh)*2+g_], 0, 0, 0); \
            } \
        __builtin_amdgcn_s_setprio(0); \
        __builtin_amdgcn_s_barrier(); \
    } while (0)

    // prologue: A(0),B(0),A(1) = 8 gloads; vmcnt(2) drains A(0)+B(0), keeps A(1).
    SA(0); SB(0); SA(1);
    asm volatile("s_waitcnt vmcnt(2)" ::: "memory");
    __builtin_amdgcn_s_barrier();

    const int NT = K >> 6;
    for (int u = 0; u < NT - 2; ++u) {
        const int X = u & 1, Y = X ^ 1;
        LOADA(X);
        PHASE(X, 0, SB(Y), "s_waitcnt vmcnt(6)");   // stage B(u+1)
        PHASE(X, 1, SA(X), "s_waitcnt vmcnt(6)");   // stage A(u+2) into dead A(X)
    }
    {   // u = NT-2: no A(NT)
        const int X = (NT - 2) & 1, Y = X ^ 1;
        LOADA(X);
        PHASE(X, 0, SB(Y), "s_waitcnt vmcnt(6)");
        PHASE(X, 1, ((void)0), "s_waitcnt vmcnt(4)");
    }
    {   // u = NT-1: drain
        const int X = (NT - 1) & 1;
        LOADA(X);
        PHASE(X, 0, ((void)0), "s_waitcnt vmcnt(0)");
        PHASE(X, 1, ((void)0), "s_nop 0");
    }
#undef PHASE
#undef LOADA
#undef SA
#undef SB

    // ---------- epilogue: per-wave LDS staging (tile buffers dead) ----------
    __syncthreads();
    float* ep = (float*)lds + wave * (16 * 68);   // 16 rows x 68 stride per wave
    #pragma unroll
    for (int f = 0; f < 4; ++f) {
        #pragma unroll
        for (int c = 0; c < 4; ++c)
            #pragma unroll
            for (int j = 0; j < 4; ++j)
                ep[(lh*4 + j) * 68 + c*16 + ll] = acc[f][c][j];
        if (OB == 0) {
            #pragma unroll
            for (int it = 0; it < 4; ++it) {
                int row = it * 4 + (l >> 4);
                const float* src = ep + row * 68 + (l & 15) * 4;
                size_t grow = (size_t)(brow + wr*64 + f*16 + row);
                *(f32x4*)((float*)Cv + grow * N + bcol + wc*64 + (l & 15) * 4) =
                    *(const f32x4*)src;
            }
        } else {
            #pragma unroll
            for (int it = 0; it < 2; ++it) {
                int row = it * 8 + (l >> 3);
                const float* src = ep + row * 68 + (l & 7) * 8;
                bf16x8 o;
                #pragma unroll
                for (int j = 0; j < 8; ++j) o[j] = (bf16)src[j];
                size_t grow = (size_t)(brow + wr*64 + f*16 + row);
                *(bf16x8*)((bf16*)Cv + grow * N + bcol + wc*64 + (l & 7) * 8) = o;
            }
        }
    }
}

// ---------------- f32 -> bf16 flat cast (8/thread) ----------------
__global__ __launch_bounds__(256) void cast_flat(const float* __restrict__ in,
                                                 bf16* __restrict__ out, int n8) {
    int i = blockIdx.x * 256 + threadIdx.x;
    if (i >= n8) return;
    float4 a = ((const float4*)in)[2 * i];
    float4 b = ((const float4*)in)[2 * i + 1];
    bf16x8 o = {(bf16)a.x, (bf16)a.y, (bf16)a.z, (bf16)a.w,
                (bf16)b.x, (bf16)b.y, (bf16)b.z, (bf16)b.w};
    *(bf16x8*)(out + (size_t)i * 8) = o;
}

// ---------------- f32 [R][C] -> bf16 [C][R] transpose-cast ----------------
__global__ __launch_bounds__(256) void cast_transpose(const float* __restrict__ in,
                                                      bf16* __restrict__ out, int R, int C) {
    __shared__ float t[64][65];
    const int r0 = blockIdx.y * 64, c0 = blockIdx.x * 64;
    #pragma unroll
    for (int i = 0; i < 4; ++i) {
        int idx = i * 256 + threadIdx.x;
        int rr = idx >> 4, c4 = (idx & 15) * 4;
        float4 v = *(const float4*)&in[(size_t)(r0 + rr) * C + c0 + c4];
        t[rr][c4] = v.x; t[rr][c4 + 1] = v.y; t[rr][c4 + 2] = v.z; t[rr][c4 + 3] = v.w;
    }
    __syncthreads();
    #pragma unroll
    for (int i = 0; i < 2; ++i) {
        int idx = i * 256 + threadIdx.x;
        int rr = idx >> 3, c8 = (idx & 7) * 8;
        bf16x8 o;
        #pragma unroll
        for (int j = 0; j < 8; ++j) o[j] = (bf16)t[c8 + j][rr];
        *(bf16x8*)&out[(size_t)(c0 + rr) * R + r0 + c8] = o;
    }
}

// ---------------- RoPE trig table ----------------
__global__ __launch_bounds__(256) void rope_table(const int* __restrict__ pos_ids,
                                                  float2* __restrict__ tab) {
    int id = blockIdx.x * 256 + threadIdx.x;   // SEQ*64
    int s = id >> 6, d = id & 63;
    float pos = (float)pos_ids[s];
    float inv = expf(-9.210340371976184f * ((float)d * (1.0f / 64.0f)));
    float sn, cs;
    sincosf(pos * inv, &sn, &cs);
    tab[id] = make_float2(cs, sn);
}

// ---------------- RoPE (NeoX) + repack q,k -> [head][seq][hd] ----------------
__global__ __launch_bounds__(256) void rope_repack(const bf16* __restrict__ qkv,
                                                   const float2* __restrict__ tab,
                                                   bf16* __restrict__ Qb,
                                                   bf16* __restrict__ Kb) {
    int id = blockIdx.x * 256 + threadIdx.x;   // SEQ*NHEAD*16
    const int d4 = (id & 15) * 4;
    const int h  = (id >> 4) & (NHEAD - 1);
    const int s  = id >> 9;

    float2 tr[4];
    #pragma unroll
    for (int i = 0; i < 4; ++i) tr[i] = tab[s * 64 + d4 + i];

    const bf16* row = qkv + (size_t)s * QKVN;
    {
        bf16x4 lo = *(const bf16x4*)(row + h * HD + d4);
        bf16x4 hi = *(const bf16x4*)(row + h * HD + 64 + d4);
        bf16x4 olo, ohi;
        #pragma unroll
        for (int i = 0; i < 4; ++i) {
            float x1 = (float)lo[i], x2 = (float)hi[i];
            olo[i] = (bf16)(x1 * tr[i].x - x2 * tr[i].y);
            ohi[i] = (bf16)(x2 * tr[i].x + x1 * tr[i].y);
        }
        bf16* qo = Qb + ((size_t)h * SEQ + s) * HD;
        *(bf16x4*)(qo + d4) = olo;
        *(bf16x4*)(qo + 64 + d4) = ohi;
    }
    {
        bf16x4 lo = *(const bf16x4*)(row + HID + h * HD + d4);
        bf16x4 hi = *(const bf16x4*)(row + HID + h * HD + 64 + d4);
        bf16x4 olo, ohi;
        #pragma unroll
        for (int i = 0; i < 4; ++i) {
            float x1 = (float)lo[i], x2 = (float)hi[i];
            olo[i] = (bf16)(x1 * tr[i].x - x2 * tr[i].y);
            ohi[i] = (bf16)(x2 * tr[i].x + x1 * tr[i].y);
        }
        bf16* ko = Kb + ((size_t)h * SEQ + s) * HD;
        *(bf16x4*)(ko + d4) = olo;
        *(bf16x4*)(ko + 64 + d4) = ohi;
    }
}

// ---------------- V transpose: qkv v-slice -> Vt [head][hd][seq] ----------------
__global__ __launch_bounds__(256) void v_transpose(const bf16* __restrict__ qkv,
                                                   bf16* __restrict__ Vt) {
    __shared__ bf16 t[64][130];
    const int h = blockIdx.y, s0 = blockIdx.x * 64;
    #pragma unroll
    for (int i = 0; i < 4; ++i) {
        int idx = i * 256 + threadIdx.x;
        int ss = idx >> 4, c8 = (idx & 15) * 8;
        bf16x8 v = *(const bf16x8*)&qkv[(size_t)(s0 + ss) * QKVN + 2 * HID + h * HD + c8];
        #pragma unroll
        for (int j = 0; j < 8; ++j) t[ss][c8 + j] = v[j];
    }
    __syncthreads();
    #pragma unroll
    for (int i = 0; i < 4; ++i) {
        int idx = i * 256 + threadIdx.x;
        int dd = idx >> 3, s8 = (idx & 7) * 8;
        bf16x8 o;
        #pragma unroll
        for (int j = 0; j < 8; ++j) o[j] = t[s8 + j][dd];
        *(bf16x8*)&Vt[((size_t)h * HD + dd) * SEQ + s0 + s8] = o;
    }
}

// ---------------- bf16 MFMA causal flash attention, 2-phase K/V dbuf ----------------
__global__ __launch_bounds__(256) void attn_mfma(const bf16* __restrict__ Qb,
                                                 const bf16* __restrict__ Kb,
                                                 const bf16* __restrict__ Vt,
                                                 bf16* __restrict__ attn) {
    __shared__ __attribute__((aligned(16))) char Ka[2][16384];
    __shared__ __attribute__((aligned(16))) char Va[2][16384];
    __shared__ __attribute__((aligned(16))) char Ps[4 * 2048];
    const int tid  = threadIdx.x, l = tid & 63, wave = tid >> 6;
    const int head = blockIdx.x;
    const int qb   = gridDim.y - 1 - blockIdx.y;
    const int q0   = qb * 64;
    const int qw   = q0 + wave * 16;
    const float scale = 0.08838834764831845f;

    bf16x8 qf[4];
    const bf16* Qg = Qb + ((size_t)head * SEQ + qw + (l & 15)) * HD;
    #pragma unroll
    for (int kc = 0; kc < 4; ++kc) qf[kc] = *(const bf16x8*)(Qg + kc * 32 + (l >> 4) * 8);

    f32x4 o[8];
    #pragma unroll
    for (int i = 0; i < 8; ++i) o[i] = (f32x4){0.f, 0.f, 0.f, 0.f};
    float mrun = -1e30f, lrun = 0.f;
    const int qrow  = qw + (l & 15);
    const int ntile = qb + 1;

    const char* Kg = (const char*)(Kb + (size_t)head * SEQ * HD);
    const char* Vg = (const char*)(Vt + (size_t)head * HD * SEQ);
    char* Pw = Ps + wave * 2048;

#define ASTAGE(b, t0) do { \
        const int kv0_ = (t0) * 64; \
        _Pragma("unroll") \
        for (int i = 0; i < 4; ++i) { \
            int c = i * 256 + tid; \
            int rk_ = c >> 4, slk_ = c & 15; \
            gload16(Kg + (size_t)(kv0_ + rk_) * 256 + ((slk_ * 16) ^ ((rk_ & 15) << 4)), \
                    Ka[b] + (size_t)(i * 256 + (tid & 192)) * 16); \
            int rv_ = c >> 3, slv_ = c & 7; \
            gload16(Vg + (size_t)rv_ * (SEQ * 2) + (size_t)kv0_ * 2 + ((slv_ * 16) ^ ((rv_ & 7) << 4)), \
                    Va[b] + (size_t)(i * 256 + (tid & 192)) * 16); \
        } \
    } while (0)

    ASTAGE(0, 0);
    asm volatile("s_waitcnt vmcnt(0)" ::: "memory");
    __builtin_amdgcn_s_barrier();

    for (int t = 0; t < ntile; ++t) {
        const int cur = t & 1;
        const int kv0 = t * 64;
        if (t + 1 < ntile) ASTAGE(cur ^ 1, t + 1);

        f32x4 st[4];
        __builtin_amdgcn_s_setprio(1);
        #pragma unroll
        for (int mf = 0; mf < 4; ++mf) {
            f32x4 s = (f32x4){0.f, 0.f, 0.f, 0.f};
            #pragma unroll
            for (int kc = 0; kc < 4; ++kc) {
                int rk = mf * 16 + (l & 15);
                bf16x8 a = *(const bf16x8*)(Ka[cur] + rk * 256 +
                              ((kc * 64 + (l >> 4) * 16) ^ ((rk & 15) << 4)));
                s = __builtin_amdgcn_mfma_f32_16x16x32_bf16(a, qf[kc], s, 0, 0, 0);
            }
            st[mf] = s;
        }
        __builtin_amdgcn_s_setprio(0);

        float pm = -1e30f;
        #pragma unroll
        for (int mf = 0; mf < 4; ++mf)
            #pragma unroll
            for (int j = 0; j < 4; ++j) {
                int kv = kv0 + mf * 16 + (l >> 4) * 4 + j;
                float v = (kv <= qrow) ? st[mf][j] * scale : -1e30f;
                st[mf][j] = v;
                pm = fmaxf(pm, v);
            }
        pm = fmaxf(pm, __shfl_xor(pm, 16));
        pm = fmaxf(pm, __shfl_xor(pm, 32));
        float mn   = fmaxf(mrun, pm);
        float corr = __expf(mrun - mn);
        float ls = 0.f;
        #pragma unroll
        for (int mf = 0; mf < 4; ++mf)
            #pragma unroll
            for (int j = 0; j < 4; ++j) {
                float p = __expf(st[mf][j] - mn);
                st[mf][j] = p;
                ls += p;
            }
        ls += __shfl_xor(ls, 16);
        ls += __shfl_xor(ls, 32);
        lrun = lrun * corr + ls;
        mrun = mn;

        f32x4 cv;
        #pragma unroll
        for (int r = 0; r < 4; ++r) cv[r] = __shfl(corr, (l >> 4) * 4 + r, 64);
        #pragma unroll
        for (int nf = 0; nf < 8; ++nf) o[nf] *= cv;

        #pragma unroll
        for (int mf = 0; mf < 4; ++mf)
            #pragma unroll
            for (int r = 0; r < 4; r += 2) {
                int kv = mf * 16 + (l >> 4) * 4 + r;
                unsigned pk = (unsigned)bbits((bf16)st[mf][r]) |
                              ((unsigned)bbits((bf16)st[mf][r + 1]) << 16);
                *(unsigned*)(Pw + (l & 15) * 128 + ((kv * 2) ^ ((l & 15 & 7) << 4))) = pk;
            }

        __builtin_amdgcn_s_setprio(1);
        #pragma unroll
        for (int kc = 0; kc < 2; ++kc) {
            bf16x8 pa = *(const bf16x8*)(Pw + (l & 15) * 128 +
                           ((kc * 64 + (l >> 4) * 16) ^ ((l & 7) << 4)));
            #pragma unroll
            for (int nf = 0; nf < 8; ++nf) {
                int dr = nf * 16 + (l & 15);
                bf16x8 vb = *(const bf16x8*)(Va[cur] + dr * 128 +
                               ((kc * 64 + (l >> 4) * 16) ^ ((dr & 7) << 4)));
                o[nf] = __builtin_amdgcn_mfma_f32_16x16x32_bf16(pa, vb, o[nf], 0, 0, 0);
            }
        }
        __builtin_amdgcn_s_setprio(0);

        asm volatile("s_waitcnt vmcnt(0) lgkmcnt(0)" ::: "memory");
        __builtin_amdgcn_s_barrier();
    }
#undef ASTAGE

    float il = 1.0f / lrun;
    f32x4 iv;
    #pragma unroll
    for (int r = 0; r < 4; ++r) iv[r] = __shfl(il, (l >> 4) * 4 + r, 64);
    #pragma unroll
    for (int nf = 0; nf < 8; ++nf)
        #pragma unroll
        for (int r = 0; r < 4; ++r) {
            int row = qw + (l >> 4) * 4 + r;
            attn[(size_t)row * HID + head * HD + nf * 16 + (l & 15)] = (bf16)(o[nf][r] * iv[r]);
        }
}

extern "C" void kernel_launch(void* const* d_in, const int* in_sizes, int n_in,
                              void* d_out, int out_size, void* d_ws, size_t ws_size,
                              hipStream_t stream) {
    const float* hidden  = (const float*)d_in[0];
    const int*   pos_ids = (const int*)d_in[1];
    const float* W_qkv   = (const float*)d_in[2];
    const float* W_o     = (const float*)d_in[3];
    float*       out     = (float*)d_out;
    char*        ws      = (char*)d_ws;

    // phase-1 layout
    bf16*   Wqkv_t   = (bf16*)(ws);                 // [12288][4096] bf16 = 100663296 B
    bf16*   qkv_b    = (bf16*)(ws + 100663296);     // [2048][12288] bf16 =  50331648 B
    bf16*   hidden_b = (bf16*)(ws + 150994944);     // [2048][4096]  bf16 =  16777216 B
    float2* tab      = (float2*)(ws + 150994944);   // reuses hidden_b slot AFTER gemm1
    // phase-2 layout (aliases Wqkv_t region, dead after GEMM1)
    bf16* Qb     = (bf16*)(ws);                     // [32][2048][128] 16 MB
    bf16* Kb     = (bf16*)(ws + 16777216);          // 16 MB
    bf16* Vtb    = (bf16*)(ws + 33554432);          // [32][128][2048] 16 MB
    bf16* attn_b = (bf16*)(ws + 50331648);          // [2048][4096] 16 MB
    bf16* Wo_t   = (bf16*)(ws + 67108864);          // [4096][4096] 32 MB

    cast_flat<<<SEQ * HID / 8 / 256, 256, 0, stream>>>(hidden, hidden_b, SEQ * HID / 8);
    cast_transpose<<<dim3(QKVN / 64, HID / 64), 256, 0, stream>>>(W_qkv, Wqkv_t, HID, QKVN);
    // GEMM1, N-split tail-free: cols 0..8191 via 256x256 (256 blocks = 1 round),
    // cols 8192..12287 via 128x256 (256 blocks = 1 round).
    gemm256<<<(8192 / 256) * (SEQ / 256), 512, 0, stream>>>(hidden_b, Wqkv_t, qkv_b,
                                                            SEQ, QKVN, HID, 0);
    gemm128n<1><<<(SEQ / 128) * (4096 / 256), 512, 0, stream>>>(hidden_b, Wqkv_t, qkv_b,
                                                                SEQ, QKVN, HID, 8192);
    rope_table<<<SEQ * 64 / 256, 256, 0, stream>>>(pos_ids, tab);
    rope_repack<<<SEQ * NHEAD * 16 / 256, 256, 0, stream>>>(qkv_b, tab, Qb, Kb);
    v_transpose<<<dim3(SEQ / 64, NHEAD), 256, 0, stream>>>(qkv_b, Vtb);
    cast_transpose<<<dim3(HID / 64, HID / 64), 256, 0, stream>>>(W_o, Wo_t, HID, HID);
    attn_mfma<<<dim3(NHEAD, SEQ / 64), 256, 0, stream>>>(Qb, Kb, Vtb, attn_b);
    // O-projection: 128x256 tiles -> 256 blocks = 1 tail-free round.
    gemm128n<0><<<(SEQ / 128) * (HID / 256), 512, 0, stream>>>(attn_b, Wo_t, out,
                                                               SEQ, HID, HID, 0);
}